// Round 1
// baseline (303.653 us; speedup 1.0000x reference)
//
#include <hip/hip_runtime.h>
#include <hip/hip_bf16.h>
#include <math.h>

typedef __attribute__((ext_vector_type(4))) float f32x4;
typedef __attribute__((ext_vector_type(8))) short s16x8;

#define B_    16
#define L_    4096
#define D_    64
#define QB    64
#define KVB   64
#define NW    4

__device__ __forceinline__ unsigned short f2bf(float x) {
  union { float f; unsigned u; } v; v.f = x;
  unsigned r = v.u + 0x7FFFu + ((v.u >> 16) & 1u);
  return (unsigned short)(r >> 16);
}

__device__ __forceinline__ int swz(int x) {
  return ((x & 7) ^ ((x >> 3) & 7)) << 4;
}

__global__ __launch_bounds__(256) void attn_fwd(
    const float* __restrict__ Qg, const float* __restrict__ Kg,
    const float* __restrict__ Vg, float* __restrict__ Og) {
  __shared__ unsigned short Ks[KVB * D_];          // [key][d], swizzled
  __shared__ unsigned short Vs[D_ * KVB];          // [d][key] (transposed), swizzled
  __shared__ unsigned short Ps[NW][16 * KVB];      // per-wave P tile, swizzled

  const int tid  = threadIdx.x;
  const int wv   = tid >> 6;
  const int lane = tid & 63;
  const int rl   = lane & 15;   // col / row-in-frag selector
  const int kb   = lane >> 4;   // k-block selector

  const int blk = blockIdx.x;
  const int b   = blk / (L_ / QB);
  const int qt  = blk % (L_ / QB);

  // ---- Q fragments: A[row=rl][k = h*32 + kb*8 + j] ----
  const float* qrow_p = Qg + ((size_t)b * L_ + qt * QB + wv * 16 + rl) * D_;
  s16x8 aq[2];
#pragma unroll
  for (int h = 0; h < 2; ++h) {
    const float* p = qrow_p + h * 32 + kb * 8;
    f32x4 x0 = *(const f32x4*)p;
    f32x4 x1 = *(const f32x4*)(p + 4);
    s16x8 w;
#pragma unroll
    for (int i = 0; i < 4; ++i) {
      w[i]     = (short)f2bf(x0[i]);
      w[i + 4] = (short)f2bf(x1[i]);
    }
    aq[h] = w;
  }

  f32x4 oacc[4];
  float m_r[4], l_r[4];
#pragma unroll
  for (int t = 0; t < 4; ++t) oacc[t] = (f32x4){0.f, 0.f, 0.f, 0.f};
#pragma unroll
  for (int j = 0; j < 4; ++j) { m_r[j] = -3.0e38f; l_r[j] = 0.f; }

  const float* kb_p = Kg + (size_t)b * L_ * D_;
  const float* vb_p = Vg + (size_t)b * L_ * D_;

  const int skey2 = (tid >> 3) * 2;  // staging: pair of keys
  const int sdseg = tid & 7;         // staging: 8-float d segment

  char* ksc = (char*)Ks;
  char* vsc = (char*)Vs;
  char* psc = (char*)(Ps[wv]);

  for (int kv = 0; kv < L_; kv += KVB) {
    __syncthreads();
    // ---- stage K (row-major) and V (transposed), fp32 -> bf16 ----
    {
      const float* kp0 = kb_p + (size_t)(kv + skey2) * D_ + sdseg * 8;
      const float* vp0 = vb_p + (size_t)(kv + skey2) * D_ + sdseg * 8;
#pragma unroll
      for (int q2 = 0; q2 < 2; ++q2) {
        const int key = skey2 + q2;
        f32x4 a0 = *(const f32x4*)(kp0 + q2 * D_);
        f32x4 a1 = *(const f32x4*)(kp0 + q2 * D_ + 4);
        s16x8 w;
#pragma unroll
        for (int i = 0; i < 4; ++i) {
          w[i]     = (short)f2bf(a0[i]);
          w[i + 4] = (short)f2bf(a1[i]);
        }
        *(s16x8*)(ksc + ((key * 128 + sdseg * 16) ^ swz(key))) = w;
      }
      f32x4 v0 = *(const f32x4*)(vp0);
      f32x4 v1 = *(const f32x4*)(vp0 + 4);
      f32x4 v2 = *(const f32x4*)(vp0 + D_);
      f32x4 v3 = *(const f32x4*)(vp0 + D_ + 4);
#pragma unroll
      for (int u = 0; u < 2; ++u) {
#pragma unroll
        for (int i = 0; i < 4; ++i) {
          const int d = sdseg * 8 + u * 4 + i;
          unsigned lo = (unsigned)f2bf(u ? v1[i] : v0[i]);
          unsigned hi = (unsigned)f2bf(u ? v3[i] : v2[i]);
          *(unsigned*)(vsc + ((d * 128 + skey2 * 2) ^ swz(d))) = lo | (hi << 16);
        }
      }
    }
    __syncthreads();

    // ---- S = Q K^T : 4 col-tiles of 16 keys, K-dim 64 = 2 MFMAs ----
    f32x4 s[4];
#pragma unroll
    for (int t = 0; t < 4; ++t) {
      const int key  = t * 16 + rl;
      const int base = key * 128 + kb * 16;
      s16x8 b0 = *(const s16x8*)(ksc + ((base)      ^ swz(key)));
      s16x8 b1 = *(const s16x8*)(ksc + ((base + 64) ^ swz(key)));
      f32x4 acc = (f32x4){0.f, 0.f, 0.f, 0.f};
      acc = __builtin_amdgcn_mfma_f32_16x16x32_bf16(aq[0], b0, acc, 0, 0, 0);
      acc = __builtin_amdgcn_mfma_f32_16x16x32_bf16(aq[1], b1, acc, 0, 0, 0);
      s[t] = acc;
    }

    // ---- scale + zero-score mask (reference fidelity) ----
#pragma unroll
    for (int t = 0; t < 4; ++t)
#pragma unroll
      for (int j = 0; j < 4; ++j) {
        float sv = s[t][j] * 0.125f;
        s[t][j] = (sv == 0.0f) ? -1e30f : sv;
      }

    // ---- online softmax: row max across 4 tiles + 16 lanes ----
    float alpha[4];
#pragma unroll
    for (int j = 0; j < 4; ++j) {
      float mx = fmaxf(fmaxf(s[0][j], s[1][j]), fmaxf(s[2][j], s[3][j]));
      mx = fmaxf(mx, __shfl_xor(mx, 1));
      mx = fmaxf(mx, __shfl_xor(mx, 2));
      mx = fmaxf(mx, __shfl_xor(mx, 4));
      mx = fmaxf(mx, __shfl_xor(mx, 8));
      const float mn = fmaxf(m_r[j], mx);
      alpha[j] = __expf(m_r[j] - mn);   // first iter: exp(-huge) = 0
      m_r[j]   = mn;
    }

    // ---- P = exp(S - m): store bf16 to per-wave LDS tile; lane-partial l ----
    float rs[4] = {0.f, 0.f, 0.f, 0.f};
#pragma unroll
    for (int t = 0; t < 4; ++t)
#pragma unroll
      for (int j = 0; j < 4; ++j) {
        const float p = __expf(s[t][j] - m_r[j]);
        rs[j] += p;
        const int row = kb * 4 + j;
        *(unsigned short*)(psc + ((row * 128 + (t * 16 + rl) * 2) ^ swz(row))) = f2bf(p);
      }
#pragma unroll
    for (int j = 0; j < 4; ++j) l_r[j] = l_r[j] * alpha[j] + rs[j];

    // ---- rescale O by alpha ----
#pragma unroll
    for (int t = 0; t < 4; ++t)
#pragma unroll
      for (int j = 0; j < 4; ++j) oacc[t][j] *= alpha[j];

    // ---- O += P V : A = P[row=rl][k=key], B = Vt[d][key] ----
    s16x8 ap[2];
#pragma unroll
    for (int h = 0; h < 2; ++h) {
      const int base = rl * 128 + h * 64 + kb * 16;
      ap[h] = *(const s16x8*)(psc + (base ^ swz(rl)));
    }
#pragma unroll
    for (int t = 0; t < 4; ++t) {
      const int d    = t * 16 + rl;
      const int base = d * 128 + kb * 16;
      s16x8 bv0 = *(const s16x8*)(vsc + ((base)      ^ swz(d)));
      s16x8 bv1 = *(const s16x8*)(vsc + ((base + 64) ^ swz(d)));
      f32x4 acc = oacc[t];
      acc = __builtin_amdgcn_mfma_f32_16x16x32_bf16(ap[0], bv0, acc, 0, 0, 0);
      acc = __builtin_amdgcn_mfma_f32_16x16x32_bf16(ap[1], bv1, acc, 0, 0, 0);
      oacc[t] = acc;
    }
  }

  // ---- epilogue: reduce l across the 16 cols, normalize, store fp32 ----
  float inv[4];
#pragma unroll
  for (int j = 0; j < 4; ++j) {
    float r = l_r[j];
    r += __shfl_xor(r, 1);
    r += __shfl_xor(r, 2);
    r += __shfl_xor(r, 4);
    r += __shfl_xor(r, 8);
    inv[j] = 1.0f / r;
  }
  float* op = Og + ((size_t)b * L_ + qt * QB + wv * 16 + kb * 4) * D_;
#pragma unroll
  for (int j = 0; j < 4; ++j)
#pragma unroll
    for (int t = 0; t < 4; ++t)
      op[(size_t)j * D_ + t * 16 + rl] = oacc[t][j] * inv[j];
}

extern "C" void kernel_launch(void* const* d_in, const int* in_sizes, int n_in,
                              void* d_out, int out_size, void* d_ws, size_t ws_size,
                              hipStream_t stream) {
  (void)in_sizes; (void)n_in; (void)d_ws; (void)ws_size; (void)out_size;
  const float* Q = (const float*)d_in[0];
  const float* K = (const float*)d_in[1];
  const float* V = (const float*)d_in[2];
  float* O = (float*)d_out;
  dim3 grid(B_ * (L_ / QB));
  attn_fwd<<<grid, 256, 0, stream>>>(Q, K, V, O);
}